// Round 15
// baseline (99.969 us; speedup 1.0000x reference)
//
#include <hip/hip_runtime.h>
#include <hip/hip_bf16.h>

// out[m,o] = sum_k x[m,k] * (W[o,k]*scale) + bias[o]
// M=1024, K=4096, N=11008.
// R15: deep pipeline. INT8 path (W pack + X per-row quant in one pre-pass,
// as R12). GEMM: 256x256 tile, 512 thr (8 waves 2Mx4N), mfma_i32_16x16x64_i8.
// LDS = 4-slot ring of K-HALVES (64 i8 cols): slot = 32KB (A 16KB + B 16KB),
// 128KB total. Half h reads slot h&3; stage(h+3) issued at half start ->
// 3 half-periods of HBM latency cover; vmcnt(12) keeps 3 halves in flight
// (never drains). Fixes vs failed R5/R6: staging stays coarse (16 rows x
// 64B contiguous per gload), and all reads target data staged 3 halves ago
// (landed + published), ordered reads-AFTER-visibility-barrier.
// Swizzle: 64B rows, 16B slot = kb ^ ((lr>>1)&3) -> 2-way banks (free);
// source pre-swizzled (l&3)^((l>>3)&3), linear gload_lds dest.

#define M_TOT 1024
#define N_TOT 11008
#define K_TOT 4096
#define BM 256
#define BN 256
#define NH (K_TOT / 64)               // 64 K-halves
#define SLOT_A_SZ 16384               // A half: 256 rows x 64 B
#define SLOT_B_  32768                // full slot: A + B

typedef __attribute__((ext_vector_type(8))) short short8;
typedef __attribute__((ext_vector_type(4))) float f32x4;
typedef __attribute__((ext_vector_type(4))) int   i32x4;

__device__ __forceinline__ unsigned short f2bf(float f) {
    __hip_bfloat16 h = __float2bfloat16(f);
    return __builtin_bit_cast(unsigned short, h);
}

__device__ __forceinline__ void gload16(const void* g, void* l) {
    __builtin_amdgcn_global_load_lds(
        (const __attribute__((address_space(1))) unsigned int*)g,
        (__attribute__((address_space(3))) unsigned int*)l,
        16, 0, 0);
}

// ---------------- merged pre-pass (R12 verbatim) ----------------
#define NPRE 3072

__global__ __launch_bounds__(256)
void prepass_kernel(const int* __restrict__ W, const float* __restrict__ X,
                    int* __restrict__ Wq, int* __restrict__ Xq,
                    float* __restrict__ sx, int wn16) {
    const int t = threadIdx.x;
    if (blockIdx.x < M_TOT) {
        const int r = blockIdx.x;
        const float* xr = X + (size_t)r * K_TOT + t * 16;
        f32x4 v[4];
        float amax = 0.0f;
#pragma unroll
        for (int j = 0; j < 4; ++j) {
            v[j] = *(const f32x4*)(xr + j * 4);
#pragma unroll
            for (int e = 0; e < 4; ++e) amax = fmaxf(amax, fabsf(v[j][e]));
        }
#pragma unroll
        for (int k = 1; k < 64; k <<= 1) amax = fmaxf(amax, __shfl_xor(amax, k));
        __shared__ float sm[4];
        if ((t & 63) == 0) sm[t >> 6] = amax;
        __syncthreads();
        amax = fmaxf(fmaxf(sm[0], sm[1]), fmaxf(sm[2], sm[3]));
        const float inv = (amax > 0.0f) ? (127.0f / amax) : 0.0f;
        if (t == 0) sx[r] = (amax > 0.0f) ? (amax / 127.0f) : 0.0f;
        i32x4 o;
#pragma unroll
        for (int j = 0; j < 4; ++j) {
            int q[4];
#pragma unroll
            for (int e = 0; e < 4; ++e) {
                int qi = (int)rintf(v[j][e] * inv);
                qi = qi > 127 ? 127 : (qi < -127 ? -127 : qi);
                q[e] = qi;
            }
            o[j] = (q[0] & 0xff) | ((q[1] & 0xff) << 8) | ((q[2] & 0xff) << 16) | (q[3] << 24);
        }
        *(i32x4*)(Xq + (size_t)r * (K_TOT / 4) + t * 4) = o;
    } else {
        int idx = (blockIdx.x - M_TOT) * blockDim.x + t;
        int stride = (NPRE - M_TOT) * blockDim.x;
        for (int i = idx; i < wn16; i += stride) {
            const int4* p = (const int4*)W + (size_t)i * 4;
            i32x4 o;
#pragma unroll
            for (int j = 0; j < 4; ++j) {
                int4 v = p[j];
                o[j] = (v.x & 0xff) | ((v.y & 0xff) << 8) | ((v.z & 0xff) << 16) | (v.w << 24);
            }
            *(i32x4*)(Wq + (size_t)i * 4) = o;
        }
    }
}

// ---------------- main GEMM: i8 NT, 256^2, depth-3 half-tile ring ----------------
__global__ __launch_bounds__(512, 2)
void gemm_i8_kernel(const char* __restrict__ Xq,    // [1024,4096] i8
                    const char* __restrict__ Wq,    // [11008,4096] i8
                    const float* __restrict__ sx,   // [1024] row scales
                    const float* __restrict__ scale,
                    const float* __restrict__ bias,
                    float* __restrict__ out) {      // [1024,11008]
    __shared__ __align__(16) unsigned char lds[4 * SLOT_B_];   // 128 KB

    const int tid  = threadIdx.x;
    const int lane = tid & 63;
    const int wid  = tid >> 6;        // 0..7
    const int wr   = wid >> 2;        // 0..1  (128-row half)
    const int wc   = wid & 3;         // 0..3  (64-col strip)
    const int lr   = lane & 15;
    const int kb   = lane >> 4;       // 0..3

    const int brow = blockIdx.y * BM;
    const int bcol = blockIdx.x * BN;

    // ---- staging: per wave per half, A 2 gloads + B 2 gloads (16 rows x 64B).
    // gload dest linear (1KB = 16 rows x 64B); lane l -> row l>>2, LDS slot l&3.
    // Source pre-swizzle so LDS slot s of row r holds k-chunk s ^ ((r>>1)&3):
    // src chunk = (l&3) ^ ((l>>3)&3).
    const int s_row  = wid * 32 + (lane >> 2);             // +16 per i
    const int s_colb = (((lane & 3) ^ ((lane >> 3) & 3)) * 16);

    const char* asrc0 = Xq + (size_t)(brow + s_row) * K_TOT + s_colb;
    const char* bsrc0 = Wq + (size_t)(bcol + s_row) * K_TOT + s_colb;
    const int lds_row0 = wid * 32;

    auto stage = [&](int h, unsigned char* slot) {
        const size_t k0 = (size_t)h * 64;
#pragma unroll
        for (int i = 0; i < 2; ++i) {
            gload16(asrc0 + k0 + (size_t)i * 16 * K_TOT, slot + (lds_row0 + i * 16) * 64);
            gload16(bsrc0 + k0 + (size_t)i * 16 * K_TOT, slot + SLOT_A_SZ + (lds_row0 + i * 16) * 64);
        }
    };

    // ---- read addressing: frag row = base + lr, 16B chunk kb at
    // slot kb ^ ((lr>>1)&3) (row bits 1-2 == lr bits 1-2; bases %16 == 0).
    const int rdoff = ((kb ^ ((lr >> 1) & 3)) * 16);

    i32x4 acc[8][4];
#pragma unroll
    for (int m = 0; m < 8; ++m)
#pragma unroll
        for (int n = 0; n < 4; ++n)
#pragma unroll
            for (int i = 0; i < 4; ++i) acc[m][n][i] = 0;

    // one K-half: reads cur (staged 3 halves ago), stages half hn -> stg
    auto do_half = [&](const unsigned char* cur, unsigned char* stg, int hn) {
        stage(hn, stg);
        asm volatile("s_waitcnt vmcnt(12)" ::: "memory");  // this half's 4 loads retired
        __builtin_amdgcn_s_barrier();                      // ...across all waves: cur visible
        __builtin_amdgcn_sched_barrier(0);

        i32x4 a0[4], a1[4], b0[4];
        // G0: B frags + A m-half0
#pragma unroll
        for (int n = 0; n < 4; ++n)
            b0[n] = *(const i32x4*)(cur + SLOT_A_SZ + (wc * 64 + n * 16 + lr) * 64 + rdoff);
#pragma unroll
        for (int m = 0; m < 4; ++m)
            a0[m] = *(const i32x4*)(cur + (wr * 128 + m * 16 + lr) * 64 + rdoff);
        // G1: A m-half1 (stays in flight under P0)
#pragma unroll
        for (int m = 0; m < 4; ++m)
            a1[m] = *(const i32x4*)(cur + (wr * 128 + 64 + m * 16 + lr) * 64 + rdoff);

        // P0
        __builtin_amdgcn_s_setprio(1);
#pragma unroll
        for (int m = 0; m < 4; ++m)
#pragma unroll
            for (int n = 0; n < 4; ++n)
                acc[m][n] = __builtin_amdgcn_mfma_i32_16x16x64_i8(a0[m], b0[n], acc[m][n], 0, 0, 0);
        __builtin_amdgcn_s_setprio(0);

        // P1 (reuse b0)
        __builtin_amdgcn_s_setprio(1);
#pragma unroll
        for (int m = 0; m < 4; ++m)
#pragma unroll
            for (int n = 0; n < 4; ++n)
                acc[4 + m][n] = __builtin_amdgcn_mfma_i32_16x16x64_i8(a1[m], b0[n], acc[4 + m][n], 0, 0, 0);
        __builtin_amdgcn_s_setprio(0);

        asm volatile("s_waitcnt lgkmcnt(0)" ::: "memory"); // all reads of cur retired
        __builtin_amdgcn_s_barrier();                      // WAR: cur's slot re-staged next half
    };

    unsigned char* s0 = lds;
    unsigned char* s1 = lds + SLOT_B_;
    unsigned char* s2 = lds + 2 * SLOT_B_;
    unsigned char* s3 = lds + 3 * SLOT_B_;

    // prologue: halves 0,1,2 -> slots 0,1,2 (12 loads in flight)
    stage(0, s0);
    stage(1, s1);
    stage(2, s2);

    // 4 halves per iteration: compile-time slot roles.
    // Half h reads slot h&3; stages half (h+3)&63 into slot (h+3)&3.
    for (int h = 0; h < NH; h += 4) {
        do_half(s0, s3, (h + 3) & (NH - 1));
        do_half(s1, s0, (h + 4) & (NH - 1));
        do_half(s2, s1, (h + 5) & (NH - 1));
        do_half(s3, s2, (h + 6) & (NH - 1));
    }

    // epilogue: out = acc * (sx[row]*scale) + bias
    const float sw = scale[0];
    const int orow0 = brow + wr * 128;
    const int ocol0 = bcol + wc * 64;
    float bv[4];
#pragma unroll
    for (int n = 0; n < 4; ++n) bv[n] = bias[ocol0 + n * 16 + lr];
#pragma unroll
    for (int m = 0; m < 8; ++m) {
        // C/D: row=(lane>>4)*4+reg, col=lane&15; rows kb*4..kb*4+3 are 4-aligned
        f32x4 sx4 = *(const f32x4*)(sx + orow0 + m * 16 + kb * 4);
#pragma unroll
        for (int i = 0; i < 4; ++i) {
            int r = orow0 + m * 16 + kb * 4 + i;
            size_t base = (size_t)r * N_TOT + ocol0;
            float fs = sx4[i] * sw;
#pragma unroll
            for (int n = 0; n < 4; ++n)
                out[base + n * 16 + lr] = (float)acc[m][n][i] * fs + bv[n];
        }
    }
}

// ---------------- fallback (round-1 fused bf16 kernel) if ws too small ----------------
__device__ __forceinline__ unsigned long long pack4(float a, float b, float c, float d) {
    return (unsigned long long)f2bf(a)
         | ((unsigned long long)f2bf(b) << 16)
         | ((unsigned long long)f2bf(c) << 32)
         | ((unsigned long long)f2bf(d) << 48);
}

#define FBM 128
#define FBN 128
#define FBK 64
#define FNT (K_TOT / FBK)

__global__ __launch_bounds__(256, 2)
void otf_linear_fused(const float* __restrict__ X, const int* __restrict__ W,
                      const float* __restrict__ scale, const float* __restrict__ bias,
                      float* __restrict__ out) {
    __shared__ __align__(16) unsigned char AsB[FBM * FBK * 2];
    __shared__ __align__(16) unsigned char BsB[FBN * FBK * 2];

    const int tid = threadIdx.x, lane = tid & 63, wid = tid >> 6;
    const int wr = wid >> 1, wc = wid & 1, lr = lane & 15, kb = lane >> 4;
    const int brow = blockIdx.y * FBM, bcol = blockIdx.x * FBN;
    const int srow = tid >> 4, sc4 = tid & 15;

    f32x4 areg[8];
    int4 breg[8];
    auto load_tiles = [&](int t) {
        const int k0 = t * FBK;
#pragma unroll
        for (int p = 0; p < 8; ++p) {
            int row = p * 16 + srow;
            areg[p] = *(const f32x4*)(&X[(size_t)(brow + row) * K_TOT + k0 + sc4 * 4]);
            breg[p] = *(const int4*)(&W[(size_t)(bcol + row) * K_TOT + k0 + sc4 * 4]);
        }
    };
    auto store_tiles = [&]() {
#pragma unroll
        for (int p = 0; p < 8; ++p) {
            int row = p * 16 + srow;
            int boff = (sc4 * 8) ^ ((row & 7) << 4);
            *(unsigned long long*)(&AsB[row * 128 + boff]) =
                pack4(areg[p][0], areg[p][1], areg[p][2], areg[p][3]);
            *(unsigned long long*)(&BsB[row * 128 + boff]) =
                pack4((float)breg[p].x, (float)breg[p].y, (float)breg[p].z, (float)breg[p].w);
        }
    };

    f32x4 acc[4][4];
#pragma unroll
    for (int m = 0; m < 4; ++m)
#pragma unroll
        for (int n = 0; n < 4; ++n)
#pragma unroll
            for (int i = 0; i < 4; ++i) acc[m][n][i] = 0.0f;

    load_tiles(0);
    for (int t = 0; t < FNT; ++t) {
        store_tiles();
        __syncthreads();
        if (t + 1 < FNT) load_tiles(t + 1);
#pragma unroll
        for (int kk = 0; kk < 2; ++kk) {
            short8 af[4], bfr[4];
#pragma unroll
            for (int m = 0; m < 4; ++m) {
                int row = wr * 64 + m * 16 + lr;
                int col = (kk * 64 + kb * 16) ^ ((row & 7) << 4);
                af[m] = *(const short8*)(&AsB[row * 128 + col]);
            }
#pragma unroll
            for (int n = 0; n < 4; ++n) {
                int row = wc * 64 + n * 16 + lr;
                int col = (kk * 64 + kb * 16) ^ ((row & 7) << 4);
                bfr[n] = *(const short8*)(&BsB[row * 128 + col]);
            }
#pragma unroll
            for (int m = 0; m < 4; ++m)
#pragma unroll
                for (int n = 0; n < 4; ++n)
                    acc[m][n] = __builtin_amdgcn_mfma_f32_16x16x32_bf16(af[m], bfr[n], acc[m][n], 0, 0, 0);
        }
        __syncthreads();
    }

    const float sc = scale[0];
    const int orow0 = brow + wr * 64, ocol0 = bcol + wc * 64;
    float bv[4];
#pragma unroll
    for (int n = 0; n < 4; ++n) bv[n] = bias[ocol0 + n * 16 + lr];
#pragma unroll
    for (int m = 0; m < 4; ++m)
#pragma unroll
        for (int i = 0; i < 4; ++i) {
            int r = orow0 + m * 16 + kb * 4 + i;
            size_t base = (size_t)r * N_TOT + ocol0;
#pragma unroll
            for (int n = 0; n < 4; ++n)
                out[base + n * 16 + lr] = acc[m][n][i] * sc + bv[n];
        }
}

extern "C" void kernel_launch(void* const* d_in, const int* in_sizes, int n_in,
                              void* d_out, int out_size, void* d_ws, size_t ws_size,
                              hipStream_t stream) {
    const float* x     = (const float*)d_in[0];
    const int*   w     = (const int*)d_in[1];
    const float* scale = (const float*)d_in[2];
    const float* bias  = (const float*)d_in[3];
    float* out = (float*)d_out;

    const size_t W_ELEMS = (size_t)N_TOT * K_TOT;   // 45,088,768
    const size_t X_ELEMS = (size_t)M_TOT * K_TOT;   //  4,194,304
    const size_t need = W_ELEMS + X_ELEMS + M_TOT * sizeof(float);  // ~49.3 MB

    if (ws_size >= need) {
        char*  Wq = (char*)d_ws;
        char*  Xq = (char*)d_ws + W_ELEMS;
        float* sx = (float*)((char*)d_ws + W_ELEMS + X_ELEMS);
        prepass_kernel<<<NPRE, 256, 0, stream>>>(w, x, (int*)Wq, (int*)Xq, sx,
                                                 (int)(W_ELEMS / 16));
        gemm_i8_kernel<<<dim3(N_TOT / BN, M_TOT / BM), 512, 0, stream>>>(
            Xq, Wq, sx, scale, bias, out);
    } else {
        otf_linear_fused<<<dim3(N_TOT / FBN, M_TOT / FBM), 256, 0, stream>>>(x, w, scale, bias, out);
    }
}

// Round 16
// 92.440 us; speedup vs baseline: 1.0814x; 1.0814x over previous
//
#include <hip/hip_runtime.h>
#include <hip/hip_bf16.h>

// out[m,o] = sum_k x[m,k] * (W[o,k]*scale) + bias[o]
// M=1024, K=4096, N=11008.
// R16 = R14/R12 verbatim (best verified: 95.1 / 94.75 us). Final kernel.
// INT8 path: W int32 -> i8 pack (exact). X f32 -> per-row i8 quant
// (row scale sx[m] = rowmax/127). GEMM mfma_i32_16x16x64_i8, 256x256 tile,
// BKI=128, 512 thr (8 waves 2Mx4N), dbuf 2x64KB LDS, row-XOR swizzle
// (pre-swizzled global source + linear gload_lds dest + swizzled ds_read),
// 2 barriers/tile: stageA(t+1) -> vmcnt(4) -> BARRIER(visibility) ->
// read/MFMA groups interleaved, stageB(t+1) mid-tile -> lgkmcnt(0) ->
// BARRIER(WAR). Epilogue: out = acc * (sx[row]*scale) + bias.
// Session ledger: schedule restructurings (4-phase, rings, half-tiles),
// W-fusion into the K-loop (2x), MFMA shape swap, XCD swizzles all
// regressed or raced; this 2-barrier structure is the robust optimum.

#define M_TOT 1024
#define N_TOT 11008
#define K_TOT 4096
#define BM 256
#define BN 256
#define BKI 128                       // K-tile in i8 elems (= 128-B rows)
#define NTI (K_TOT / BKI)             // 32 K-tiles (even)
#define ABYTES (BM * BKI)             // 32 KB
#define BUFB   ((BM + BN) * BKI)      // 64 KB per buffer

typedef __attribute__((ext_vector_type(8))) short short8;
typedef __attribute__((ext_vector_type(4))) float f32x4;
typedef __attribute__((ext_vector_type(4))) int   i32x4;

__device__ __forceinline__ unsigned short f2bf(float f) {
    __hip_bfloat16 h = __float2bfloat16(f);
    return __builtin_bit_cast(unsigned short, h);
}

__device__ __forceinline__ void gload16(const void* g, void* l) {
    __builtin_amdgcn_global_load_lds(
        (const __attribute__((address_space(1))) unsigned int*)g,
        (__attribute__((address_space(3))) unsigned int*)l,
        16, 0, 0);
}

// ---------------- merged pre-pass ----------------
// blocks [0, 1024): xquant row r = blockIdx.x (256 thr, 16 f32 each)
// blocks [1024, NPRE): wpack grid-stride over W (64B read -> 16B write / thr)
#define NPRE 3072

__global__ __launch_bounds__(256)
void prepass_kernel(const int* __restrict__ W, const float* __restrict__ X,
                    int* __restrict__ Wq, int* __restrict__ Xq,
                    float* __restrict__ sx, int wn16) {
    const int t = threadIdx.x;
    if (blockIdx.x < M_TOT) {
        // ---- xquant: one block per row ----
        const int r = blockIdx.x;
        const float* xr = X + (size_t)r * K_TOT + t * 16;
        f32x4 v[4];
        float amax = 0.0f;
#pragma unroll
        for (int j = 0; j < 4; ++j) {
            v[j] = *(const f32x4*)(xr + j * 4);
#pragma unroll
            for (int e = 0; e < 4; ++e) amax = fmaxf(amax, fabsf(v[j][e]));
        }
#pragma unroll
        for (int k = 1; k < 64; k <<= 1) amax = fmaxf(amax, __shfl_xor(amax, k));
        __shared__ float sm[4];
        if ((t & 63) == 0) sm[t >> 6] = amax;
        __syncthreads();
        amax = fmaxf(fmaxf(sm[0], sm[1]), fmaxf(sm[2], sm[3]));
        const float inv = (amax > 0.0f) ? (127.0f / amax) : 0.0f;
        if (t == 0) sx[r] = (amax > 0.0f) ? (amax / 127.0f) : 0.0f;
        i32x4 o;
#pragma unroll
        for (int j = 0; j < 4; ++j) {
            int q[4];
#pragma unroll
            for (int e = 0; e < 4; ++e) {
                int qi = (int)rintf(v[j][e] * inv);
                qi = qi > 127 ? 127 : (qi < -127 ? -127 : qi);
                q[e] = qi;
            }
            o[j] = (q[0] & 0xff) | ((q[1] & 0xff) << 8) | ((q[2] & 0xff) << 16) | (q[3] << 24);
        }
        *(i32x4*)(Xq + (size_t)r * (K_TOT / 4) + t * 4) = o;
    } else {
        // ---- wpack: grid-stride ----
        int idx = (blockIdx.x - M_TOT) * blockDim.x + t;
        int stride = (NPRE - M_TOT) * blockDim.x;
        for (int i = idx; i < wn16; i += stride) {
            const int4* p = (const int4*)W + (size_t)i * 4;
            i32x4 o;
#pragma unroll
            for (int j = 0; j < 4; ++j) {
                int4 v = p[j];
                o[j] = (v.x & 0xff) | ((v.y & 0xff) << 8) | ((v.z & 0xff) << 16) | (v.w << 24);
            }
            *(i32x4*)(Wq + (size_t)i * 4) = o;
        }
    }
}

// ---------------- main GEMM: i8 NT, 256^2, R8 schedule (verbatim) ----------------
__global__ __launch_bounds__(512, 2)
void gemm_i8_kernel(const char* __restrict__ Xq,    // [1024,4096] i8
                    const char* __restrict__ Wq,    // [11008,4096] i8
                    const float* __restrict__ sx,   // [1024] row scales
                    const float* __restrict__ scale,
                    const float* __restrict__ bias,
                    float* __restrict__ out) {      // [1024,11008]
    __shared__ __align__(16) unsigned char lds[2 * BUFB];   // 128 KB

    const int tid  = threadIdx.x;
    const int lane = tid & 63;
    const int wid  = tid >> 6;        // 0..7
    const int wr   = wid >> 2;        // 0..1  (128-row half)
    const int wc   = wid & 3;         // 0..3  (64-col strip)
    const int lr   = lane & 15;
    const int kb   = lane >> 4;       // 0..3

    const int brow = blockIdx.y * BM;
    const int bcol = blockIdx.x * BN;

    // staging: per wave 32 rows A + 32 rows B (128 B each) = 4+4 gloads.
    // gload_lds dest linear; global source 16B-slot pre-swizzled:
    // src slot = (l&7) ^ (l>>3)  (row-in-chunk = l>>3).
    const int s_row  = wid * 32 + (lane >> 3);
    const int s_colb = (((lane & 7) ^ (lane >> 3)) * 16);   // bytes

    const char* asrc0 = Xq + (size_t)(brow + s_row) * K_TOT + s_colb;
    const char* bsrc0 = Wq + (size_t)(bcol + s_row) * K_TOT + s_colb;
    const int lds_row0 = wid * 32;

    auto stageA = [&](int t, unsigned char* buf) {
        const size_t k0 = (size_t)t * BKI;
#pragma unroll
        for (int i = 0; i < 4; ++i)
            gload16(asrc0 + k0 + (size_t)i * 8 * K_TOT, buf + (lds_row0 + i * 8) * BKI);
    };
    auto stageB = [&](int t, unsigned char* buf) {
        const size_t k0 = (size_t)t * BKI;
#pragma unroll
        for (int i = 0; i < 4; ++i)
            gload16(bsrc0 + k0 + (size_t)i * 8 * K_TOT, buf + ABYTES + (lds_row0 + i * 8) * BKI);
    };

    i32x4 acc[8][4];
#pragma unroll
    for (int m = 0; m < 8; ++m)
#pragma unroll
        for (int n = 0; n < 4; ++n)
#pragma unroll
            for (int i = 0; i < 4; ++i) acc[m][n][i] = 0;

    // one K-tile (K=128): reads cur, stages tile tn -> nxt
    auto do_tile = [&](const unsigned char* cur, unsigned char* nxt, int tn) {
        stageA(tn, nxt);
        asm volatile("s_waitcnt vmcnt(4)" ::: "memory");   // tile-t A,B landed (this wave)
        __builtin_amdgcn_s_barrier();                      // all waves' => cur visible
        __builtin_amdgcn_sched_barrier(0);

        i32x4 a0[4], a1[4], a2[4], a3[4], b0[4], b1[4];
        const int c0 = (kb * 16);          // kk=0 byte col (slot kb)
        const int c1 = (64 + kb * 16);     // kk=1 byte col (slot 4+kb)

        // G0: B(kk0) + A(kk0, m-half0)
#pragma unroll
        for (int n = 0; n < 4; ++n) {
            int row = wc * 64 + n * 16 + lr;
            b0[n] = *(const i32x4*)(cur + ABYTES + row * BKI + (c0 ^ ((row & 7) << 4)));
        }
#pragma unroll
        for (int m = 0; m < 4; ++m) {
            int row = wr * 128 + m * 16 + lr;
            a0[m] = *(const i32x4*)(cur + row * BKI + (c0 ^ ((row & 7) << 4)));
        }
        // G1: A(kk0, m-half1)
#pragma unroll
        for (int m = 0; m < 4; ++m) {
            int row = wr * 128 + 64 + m * 16 + lr;
            a1[m] = *(const i32x4*)(cur + row * BKI + (c0 ^ ((row & 7) << 4)));
        }

        // P0
        __builtin_amdgcn_s_setprio(1);
#pragma unroll
        for (int m = 0; m < 4; ++m)
#pragma unroll
            for (int n = 0; n < 4; ++n)
                acc[m][n] = __builtin_amdgcn_mfma_i32_16x16x64_i8(a0[m], b0[n], acc[m][n], 0, 0, 0);
        __builtin_amdgcn_s_setprio(0);

        // G2: B(kk1) + A(kk1, m-half0)
#pragma unroll
        for (int n = 0; n < 4; ++n) {
            int row = wc * 64 + n * 16 + lr;
            b1[n] = *(const i32x4*)(cur + ABYTES + row * BKI + (c1 ^ ((row & 7) << 4)));
        }
#pragma unroll
        for (int m = 0; m < 4; ++m) {
            int row = wr * 128 + m * 16 + lr;
            a2[m] = *(const i32x4*)(cur + row * BKI + (c1 ^ ((row & 7) << 4)));
        }

        // P1
        __builtin_amdgcn_s_setprio(1);
#pragma unroll
        for (int m = 0; m < 4; ++m)
#pragma unroll
            for (int n = 0; n < 4; ++n)
                acc[4 + m][n] = __builtin_amdgcn_mfma_i32_16x16x64_i8(a1[m], b0[n], acc[4 + m][n], 0, 0, 0);
        __builtin_amdgcn_s_setprio(0);

        // G3: A(kk1, m-half1); stage B of next tile mid-compute
#pragma unroll
        for (int m = 0; m < 4; ++m) {
            int row = wr * 128 + 64 + m * 16 + lr;
            a3[m] = *(const i32x4*)(cur + row * BKI + (c1 ^ ((row & 7) << 4)));
        }
        stageB(tn, nxt);

        // P2
        __builtin_amdgcn_s_setprio(1);
#pragma unroll
        for (int m = 0; m < 4; ++m)
#pragma unroll
            for (int n = 0; n < 4; ++n)
                acc[m][n] = __builtin_amdgcn_mfma_i32_16x16x64_i8(a2[m], b1[n], acc[m][n], 0, 0, 0);
        __builtin_amdgcn_s_setprio(0);

        // P3
        __builtin_amdgcn_s_setprio(1);
#pragma unroll
        for (int m = 0; m < 4; ++m)
#pragma unroll
            for (int n = 0; n < 4; ++n)
                acc[4 + m][n] = __builtin_amdgcn_mfma_i32_16x16x64_i8(a3[m], b1[n], acc[4 + m][n], 0, 0, 0);
        __builtin_amdgcn_s_setprio(0);

        asm volatile("s_waitcnt lgkmcnt(0)" ::: "memory");
        __builtin_amdgcn_s_barrier();                      // WAR: cur re-staged next tile
    };

    unsigned char* buf0 = lds;
    unsigned char* buf1 = lds + BUFB;

    stageA(0, buf0);
    stageB(0, buf0);

    for (int t = 0; t < NTI; t += 2) {
        do_tile(buf0, buf1, t + 1);
        do_tile(buf1, buf0, (t + 2 < NTI) ? t + 2 : 0);
    }

    // epilogue: out = acc * (sx[row]*scale) + bias
    const float sw = scale[0];
    const int orow0 = brow + wr * 128;
    const int ocol0 = bcol + wc * 64;
    float bv[4];
#pragma unroll
    for (int n = 0; n < 4; ++n) bv[n] = bias[ocol0 + n * 16 + lr];
#pragma unroll
    for (int m = 0; m < 8; ++m) {
        // C/D: row=(lane>>4)*4+reg, col=lane&15; rows kb*4..kb*4+3 are 4-aligned
        f32x4 sx4 = *(const f32x4*)(sx + orow0 + m * 16 + kb * 4);
#pragma unroll
        for (int i = 0; i < 4; ++i) {
            int r = orow0 + m * 16 + kb * 4 + i;
            size_t base = (size_t)r * N_TOT + ocol0;
            float fs = sx4[i] * sw;
#pragma unroll
            for (int n = 0; n < 4; ++n)
                out[base + n * 16 + lr] = (float)acc[m][n][i] * fs + bv[n];
        }
    }
}

// ---------------- fallback (round-1 fused bf16 kernel) if ws too small ----------------
__device__ __forceinline__ unsigned long long pack4(float a, float b, float c, float d) {
    return (unsigned long long)f2bf(a)
         | ((unsigned long long)f2bf(b) << 16)
         | ((unsigned long long)f2bf(c) << 32)
         | ((unsigned long long)f2bf(d) << 48);
}

#define FBM 128
#define FBN 128
#define FBK 64
#define FNT (K_TOT / FBK)

__global__ __launch_bounds__(256, 2)
void otf_linear_fused(const float* __restrict__ X, const int* __restrict__ W,
                      const float* __restrict__ scale, const float* __restrict__ bias,
                      float* __restrict__ out) {
    __shared__ __align__(16) unsigned char AsB[FBM * FBK * 2];
    __shared__ __align__(16) unsigned char BsB[FBN * FBK * 2];

    const int tid = threadIdx.x, lane = tid & 63, wid = tid >> 6;
    const int wr = wid >> 1, wc = wid & 1, lr = lane & 15, kb = lane >> 4;
    const int brow = blockIdx.y * FBM, bcol = blockIdx.x * FBN;
    const int srow = tid >> 4, sc4 = tid & 15;

    f32x4 areg[8];
    int4 breg[8];
    auto load_tiles = [&](int t) {
        const int k0 = t * FBK;
#pragma unroll
        for (int p = 0; p < 8; ++p) {
            int row = p * 16 + srow;
            areg[p] = *(const f32x4*)(&X[(size_t)(brow + row) * K_TOT + k0 + sc4 * 4]);
            breg[p] = *(const int4*)(&W[(size_t)(bcol + row) * K_TOT + k0 + sc4 * 4]);
        }
    };
    auto store_tiles = [&]() {
#pragma unroll
        for (int p = 0; p < 8; ++p) {
            int row = p * 16 + srow;
            int boff = (sc4 * 8) ^ ((row & 7) << 4);
            *(unsigned long long*)(&AsB[row * 128 + boff]) =
                pack4(areg[p][0], areg[p][1], areg[p][2], areg[p][3]);
            *(unsigned long long*)(&BsB[row * 128 + boff]) =
                pack4((float)breg[p].x, (float)breg[p].y, (float)breg[p].z, (float)breg[p].w);
        }
    };

    f32x4 acc[4][4];
#pragma unroll
    for (int m = 0; m < 4; ++m)
#pragma unroll
        for (int n = 0; n < 4; ++n)
#pragma unroll
            for (int i = 0; i < 4; ++i) acc[m][n][i] = 0.0f;

    load_tiles(0);
    for (int t = 0; t < FNT; ++t) {
        store_tiles();
        __syncthreads();
        if (t + 1 < FNT) load_tiles(t + 1);
#pragma unroll
        for (int kk = 0; kk < 2; ++kk) {
            short8 af[4], bfr[4];
#pragma unroll
            for (int m = 0; m < 4; ++m) {
                int row = wr * 64 + m * 16 + lr;
                int col = (kk * 64 + kb * 16) ^ ((row & 7) << 4);
                af[m] = *(const short8*)(&AsB[row * 128 + col]);
            }
#pragma unroll
            for (int n = 0; n < 4; ++n) {
                int row = wc * 64 + n * 16 + lr;
                int col = (kk * 64 + kb * 16) ^ ((row & 7) << 4);
                bfr[n] = *(const short8*)(&BsB[row * 128 + col]);
            }
#pragma unroll
            for (int m = 0; m < 4; ++m)
#pragma unroll
                for (int n = 0; n < 4; ++n)
                    acc[m][n] = __builtin_amdgcn_mfma_f32_16x16x32_bf16(af[m], bfr[n], acc[m][n], 0, 0, 0);
        }
        __syncthreads();
    }

    const float sc = scale[0];
    const int orow0 = brow + wr * 64, ocol0 = bcol + wc * 64;
    float bv[4];
#pragma unroll
    for (int n = 0; n < 4; ++n) bv[n] = bias[ocol0 + n * 16 + lr];
#pragma unroll
    for (int m = 0; m < 4; ++m)
#pragma unroll
        for (int i = 0; i < 4; ++i) {
            int r = orow0 + m * 16 + kb * 4 + i;
            size_t base = (size_t)r * N_TOT + ocol0;
#pragma unroll
            for (int n = 0; n < 4; ++n)
                out[base + n * 16 + lr] = acc[m][n][i] * sc + bv[n];
        }
}

extern "C" void kernel_launch(void* const* d_in, const int* in_sizes, int n_in,
                              void* d_out, int out_size, void* d_ws, size_t ws_size,
                              hipStream_t stream) {
    const float* x     = (const float*)d_in[0];
    const int*   w     = (const int*)d_in[1];
    const float* scale = (const float*)d_in[2];
    const float* bias  = (const float*)d_in[3];
    float* out = (float*)d_out;

    const size_t W_ELEMS = (size_t)N_TOT * K_TOT;   // 45,088,768
    const size_t X_ELEMS = (size_t)M_TOT * K_TOT;   //  4,194,304
    const size_t need = W_ELEMS + X_ELEMS + M_TOT * sizeof(float);  // ~49.3 MB

    if (ws_size >= need) {
        char*  Wq = (char*)d_ws;
        char*  Xq = (char*)d_ws + W_ELEMS;
        float* sx = (float*)((char*)d_ws + W_ELEMS + X_ELEMS);
        prepass_kernel<<<NPRE, 256, 0, stream>>>(w, x, (int*)Wq, (int*)Xq, sx,
                                                 (int)(W_ELEMS / 16));
        gemm_i8_kernel<<<dim3(N_TOT / BN, M_TOT / BM), 512, 0, stream>>>(
            Xq, Wq, sx, scale, bias, out);
    } else {
        otf_linear_fused<<<dim3(N_TOT / FBN, M_TOT / FBM), 256, 0, stream>>>(x, w, scale, bias, out);
    }
}